// Round 5
// baseline (594.125 us; speedup 1.0000x reference)
//
#include <hip/hip_runtime.h>
#include <hip/hip_bf16.h>

#define K30REV 4.77464829275686f   /* 30/(2*pi) */
#define ASTRIDE 272                /* A-tile row stride in bytes: 256 + 16 pad */

typedef __attribute__((ext_vector_type(4))) float f32x4;
typedef __attribute__((ext_vector_type(8))) short s16x8;

__device__ __forceinline__ short f2bf(float f) {
    union { float f; unsigned u; } a; a.f = f;
    unsigned r = a.u + 0x7fffu + ((a.u >> 16) & 1u);
    return (short)(r >> 16);
}

__device__ __forceinline__ unsigned pk2(float a, float b) {
    union { __hip_bfloat162 h; unsigned u; } cv;
    cv.h = __float22bfloat162_rn(make_float2(a, b));
    return cv.u;
}

// ---------- merged prep: k-traj tables | weights->bf16 | bias prescale | axis phase tables ----------
__global__ void k_prep(const float* __restrict__ ktraj,
                       const float* __restrict__ W0, const float* __restrict__ W1,
                       const float* __restrict__ W2, const float* __restrict__ W3,
                       const float* __restrict__ W4,
                       const float* __restrict__ b0, const float* __restrict__ b1,
                       const float* __restrict__ b2, const float* __restrict__ b3,
                       const float* __restrict__ Bmat,
                       float* __restrict__ tab, short* __restrict__ wbf,
                       float* __restrict__ brev,
                       float* __restrict__ ptx, float* __restrict__ pty,
                       float* __restrict__ ptz) {
    int i = blockIdx.x * 256 + threadIdx.x;
    if (i < 524288) {
        int n = i >> 8, s = i & 255;
        if (s < 128) {
            float a = ktraj[n] * (float)s;
            tab[n * 512 + s]       = __cosf(a);
            tab[n * 512 + 128 + s] = __sinf(a);
        } else {
            int y = s - 128;
            float a = ktraj[2048 + n] * (float)y;
            tab[n * 512 + 256 + y] = __cosf(a);
            tab[n * 512 + 384 + y] = __sinf(a);
        }
        return;
    }
    i -= 524288;
    if (i < 65536) {
        int w = i >> 14;
        const float* src = (w == 0) ? W0 : (w == 1) ? W1 : (w == 2) ? W2 : W3;
        wbf[i] = f2bf(src[i & 16383]);
        return;
    }
    i -= 65536;
    if (i < 2048) {
        int row = i >> 7, col = i & 127;
        wbf[65536 + i] = f2bf(row == 0 ? W4[col] : 0.0f);
        return;
    }
    i -= 2048;
    if (i < 512) {
        int l = i >> 7, col = i & 127;
        const float* src = (l == 0) ? b0 : (l == 1) ? b1 : (l == 2) ? b2 : b3;
        brev[i] = src[col] * K30REV;
        return;
    }
    i -= 512;
    if (i < 8192) {             // ptx
        int x = i >> 6, e = i & 63;
        ptx[i] = ((x + 0.5f) * (1.0f / 128.0f)) * Bmat[e * 3 + 0];
        return;
    }
    i -= 8192;
    if (i < 8192) {             // pty
        int y = i >> 6, e = i & 63;
        pty[i] = ((y + 0.5f) * (1.0f / 128.0f)) * Bmat[e * 3 + 1];
        return;
    }
    i -= 8192;
    if (i < 4096) {             // ptz
        int z = i >> 6, e = i & 63;
        ptz[i] = ((z + 0.5f) * (1.0f / 64.0f)) * Bmat[e * 3 + 2];
    }
}

// ---------- kernel 1: fused encode + SIREN + (vol - image), ZERO barriers ----------
// Block = 256 thr = 4 waves. Each wave privately owns 32 rows x all 128 neurons:
// A rows [32][272B] per wave (pad 16B -> conflict-free b128 reads), acc[2][8] =
// 64 AGPR, af = W fragments streamed from global (L1-hot: all waves share the
// same 32 KB/layer). No __syncthreads anywhere: encode, layer read/write, and
// output are wave-private; write->read ordering is per-wave data dependence.
// 34 KB LDS -> 4 blocks/CU -> 16 independent waves/CU (no lockstep drains).
// Swapped MFMA: mfma(af=W rows, bf=A rows) -> lane: A-row=l15, neuron=l4*4+jj
// -> activation writeback = one ds_write_b64 (4 consecutive bf16 cols).
__launch_bounds__(256, 4)
__global__ void k_siren(const float* __restrict__ ptx, const float* __restrict__ pty,
                        const float* __restrict__ ptz,
                        const float* __restrict__ brev,
                        const float* __restrict__ b4,
                        const short* __restrict__ wbf,
                        const float* __restrict__ image,
                        float* __restrict__ d_nat) {
    __shared__ alignas(16) char Abuf[128 * ASTRIDE];   // 34816 B
    const int tid  = threadIdx.x;
    const int lane = tid & 63;
    const int w    = tid >> 6;      // wave: rows w*32 .. w*32+31 (tid 64w..64w+63)
    const int l15  = lane & 15;
    const int l4   = lane >> 4;
    const int nbase = blockIdx.x * 128;

    // ---- encode: 2 threads per row, 32 freqs each (rows are wave-local) ----
    {
        int row = tid >> 1, h = tid & 1;
        int n = nbase + row;
        int x = n >> 13, y = (n >> 6) & 127, z = n & 63;
        const float* pxr = ptx + x * 64 + h * 32;
        const float* pyr = pty + y * 64 + h * 32;
        const float* pzr = ptz + z * 64 + h * 32;
        char* rowp = Abuf + row * ASTRIDE + h * 64;
        #pragma unroll
        for (int eb = 0; eb < 32; eb += 8) {
            f32x4 xa = *(const f32x4*)(pxr + eb),     xb = *(const f32x4*)(pxr + eb + 4);
            f32x4 ya = *(const f32x4*)(pyr + eb),     yb = *(const f32x4*)(pyr + eb + 4);
            f32x4 za = *(const f32x4*)(pzr + eb),     zb = *(const f32x4*)(pzr + eb + 4);
            float p[8];
            #pragma unroll
            for (int j = 0; j < 4; j++) {
                p[j]     = xa[j] + ya[j] + za[j];
                p[4 + j] = xb[j] + yb[j] + zb[j];
            }
            unsigned vs[4], vc[4];
            #pragma unroll
            for (int j = 0; j < 4; j++) {
                vs[j] = pk2(__builtin_amdgcn_sinf(p[2 * j]), __builtin_amdgcn_sinf(p[2 * j + 1]));
                vc[j] = pk2(__builtin_amdgcn_cosf(p[2 * j]), __builtin_amdgcn_cosf(p[2 * j + 1]));
            }
            *(uint4*)(rowp + 2 * eb)       = *(uint4*)vs;   // sin block: bytes 0..127
            *(uint4*)(rowp + 128 + 2 * eb) = *(uint4*)vc;   // cos block: bytes 128..255
        }
    }

    // ---- layer-invariant addresses (wave-private rows) ----
    int rbase[2], wbase[2];
    #pragma unroll
    for (int rt = 0; rt < 2; rt++) {
        int rowoff = (w * 32 + rt * 16 + l15) * ASTRIDE;
        rbase[rt] = rowoff + l4 * 16;   // + ks*64 on read
        wbase[rt] = rowoff + l4 * 8;    // + nt*32 on write
    }

    // ---- 4 hidden layers (no barriers: all deps are in-wave) ----
    #pragma unroll 1
    for (int layer = 0; layer < 4; layer++) {
        const short* W = wbf + layer * 16384 + l15 * 128 + l4 * 8;
        f32x4 acc[2][8];
        #pragma unroll
        for (int nt = 0; nt < 8; nt++) {
            acc[0][nt] = (f32x4){0.f, 0.f, 0.f, 0.f};
            acc[1][nt] = (f32x4){0.f, 0.f, 0.f, 0.f};
        }
        #pragma unroll
        for (int ks = 0; ks < 4; ks++) {
            s16x8 bf0 = *(const s16x8*)(Abuf + rbase[0] + ks * 64);
            s16x8 bf1 = *(const s16x8*)(Abuf + rbase[1] + ks * 64);
            #pragma unroll
            for (int nt = 0; nt < 8; nt++) {
                s16x8 af = *(const s16x8*)(W + nt * 2048 + ks * 32);
                acc[0][nt] = __builtin_amdgcn_mfma_f32_16x16x32_bf16(af, bf0, acc[0][nt], 0, 0, 0);
                acc[1][nt] = __builtin_amdgcn_mfma_f32_16x16x32_bf16(af, bf1, acc[1][nt], 0, 0, 0);
            }
        }
        #pragma unroll
        for (int nt = 0; nt < 8; nt++) {
            f32x4 bb = *(const f32x4*)(brev + layer * 128 + nt * 16 + l4 * 4);
            #pragma unroll
            for (int rt = 0; rt < 2; rt++) {
                float s0 = __builtin_amdgcn_sinf(fmaf(acc[rt][nt][0], K30REV, bb[0]));
                float s1 = __builtin_amdgcn_sinf(fmaf(acc[rt][nt][1], K30REV, bb[1]));
                float s2 = __builtin_amdgcn_sinf(fmaf(acc[rt][nt][2], K30REV, bb[2]));
                float s3 = __builtin_amdgcn_sinf(fmaf(acc[rt][nt][3], K30REV, bb[3]));
                uint2 pk; pk.x = pk2(s0, s1); pk.y = pk2(s2, s3);
                *(uint2*)(Abuf + wbase[rt] + nt * 32) = pk;
            }
        }
    }

    // ---- final layer (unswapped): af=A rows, bf=W4 padded; 2 row-tiles per wave ----
    {
        const short* W4p = wbf + 65536 + l15 * 128 + l4 * 8;
        f32x4 a4[2];
        a4[0] = (f32x4){0.f, 0.f, 0.f, 0.f};
        a4[1] = (f32x4){0.f, 0.f, 0.f, 0.f};
        #pragma unroll
        for (int ks = 0; ks < 4; ks++) {
            s16x8 bw = *(const s16x8*)(W4p + ks * 32);
            #pragma unroll
            for (int q = 0; q < 2; q++) {
                int row = w * 32 + q * 16 + l15;
                s16x8 af = *(const s16x8*)(Abuf + row * ASTRIDE + ks * 64 + l4 * 16);
                a4[q] = __builtin_amdgcn_mfma_f32_16x16x32_bf16(af, bw, a4[q], 0, 0, 0);
            }
        }
        if (l15 == 0) {
            float b4v = b4[0];
            #pragma unroll
            for (int q = 0; q < 2; q++) {
                int n = nbase + w * 32 + q * 16 + l4 * 4;
                const f32x4 img = *(const f32x4*)(image + n);
                f32x4 dv;
                #pragma unroll
                for (int jj = 0; jj < 4; jj++) dv[jj] = a4[q][jj] + b4v - img[jj];
                *(f32x4*)(d_nat + n) = dv;
            }
        }
    }
}

// ---------- kernel 1.5: d_nat [x][y][z] fp32 -> d_proj [z][x*128+y] bf16 ----------
__global__ void k_transpose(const float* __restrict__ d_nat, short* __restrict__ d_proj) {
    __shared__ float t[128][65];
    int x = blockIdx.x;
    for (int i = threadIdx.x; i < 8192; i += 256)
        t[i >> 6][i & 63] = d_nat[x * 8192 + i];
    __syncthreads();
    for (int i = threadIdx.x; i < 8192; i += 256) {
        int z = i >> 7, y = i & 127;
        d_proj[z * 16384 + x * 128 + y] = f2bf(t[y][z]);
    }
}

// ---------- kernel 2: NUDFT GEMM (M=64 z, N=2048 k-samples, K=16384 pixels) ----------
__launch_bounds__(256, 2)
__global__ void k_project(const short* __restrict__ d_proj, const float* __restrict__ tab,
                          float* __restrict__ part) {
    __shared__ alignas(16) float lt[4 * 32 * 132];   // 67584 B; reused as reduce buffer
    const int tid  = threadIdx.x;
    const int lane = tid & 63;
    const int w    = tid >> 6;
    const int l15  = lane & 15;
    const int l4   = lane >> 4;
    const int nblk = blockIdx.x & 63;
    const int ksp  = blockIdx.x >> 6;
    const int nbase = nblk * 32;

    for (int i = tid; i < 16384; i += 256) {
        int nl = i >> 9, r = i & 511;
        int t = r >> 7, e = r & 127;
        lt[(t * 32 + nl) * 132 + e] = tab[(nbase + nl) * 512 + r];
    }
    __syncthreads();

    f32x4 ar[4][2], ai[4][2];
    #pragma unroll
    for (int rt = 0; rt < 4; rt++)
        #pragma unroll
        for (int nt = 0; nt < 2; nt++) {
            ar[rt][nt] = (f32x4){0.f, 0.f, 0.f, 0.f};
            ai[rt][nt] = (f32x4){0.f, 0.f, 0.f, 0.f};
        }

    const int p2base = ksp * 2048 + w * 512;
    #pragma unroll 1
    for (int ks = 0; ks < 16; ks++) {
        int p2c = p2base + ks * 32;
        s16x8 afr[4];
        #pragma unroll
        for (int rt = 0; rt < 4; rt++)
            afr[rt] = *(const s16x8*)(d_proj + (rt * 16 + l15) * 16384 + p2c + l4 * 8);
        int p2 = p2c + l4 * 8;
        int x = p2 >> 7, y0 = p2 & 127;
        #pragma unroll
        for (int nt = 0; nt < 2; nt++) {
            int nl = nt * 16 + l15;
            float cA = lt[nl * 132 + x];
            float sA = lt[(32 + nl) * 132 + x];
            const float* cB = &lt[(64 + nl) * 132 + y0];
            const float* sB = &lt[(96 + nl) * 132 + y0];
            s16x8 bc, bs;
            #pragma unroll
            for (int j = 0; j < 8; j++) {
                float cb = cB[j], sb = sB[j];
                bc[j] = f2bf(cA * cb - sA * sb);
                bs[j] = f2bf(sA * cb + cA * sb);
            }
            #pragma unroll
            for (int rt = 0; rt < 4; rt++) {
                ar[rt][nt] = __builtin_amdgcn_mfma_f32_16x16x32_bf16(afr[rt], bc, ar[rt][nt], 0, 0, 0);
                ai[rt][nt] = __builtin_amdgcn_mfma_f32_16x16x32_bf16(afr[rt], bs, ai[rt][nt], 0, 0, 0);
            }
        }
    }
    __syncthreads();   // tables dead; reuse lt as reduce buffer
    float* red = lt;
    #pragma unroll
    for (int rt = 0; rt < 4; rt++)
        #pragma unroll
        for (int nt = 0; nt < 2; nt++)
            #pragma unroll
            for (int jj = 0; jj < 4; jj++) {
                int z = rt * 16 + l4 * 4 + jj;
                int q = nt * 16 + l15;
                red[(w * 64 + z) * 64 + q * 2 + 0] = ar[rt][nt][jj];
                red[(w * 64 + z) * 64 + q * 2 + 1] = ai[rt][nt][jj];
            }
    __syncthreads();
    for (int i = tid; i < 4096; i += 256) {
        int z = i >> 6, q = i & 63;
        float s = red[z * 64 + q] + red[4096 + z * 64 + q] + red[8192 + z * 64 + q] + red[12288 + z * 64 + q];
        part[((ksp * 64 + z) * 2048 + nbase + (q >> 1)) * 2 + (q & 1)] = s;
    }
}

// ---------- kernel 3: sum K-split partials, square, reduce to loss ----------
__global__ void k_loss(const float* __restrict__ part, float* __restrict__ out) {
    int g = blockIdx.x * 256 + threadIdx.x;   // 131072 (z,n) pairs
    int z = g >> 11, n = g & 2047;
    float r = 0.f, im = 0.f;
    #pragma unroll
    for (int ksp = 0; ksp < 8; ksp++) {
        const float2 v = *(const float2*)(part + ((ksp * 64 + z) * 2048 + n) * 2);
        r += v.x; im += v.y;
    }
    float val = r * r + im * im;
    #pragma unroll
    for (int o = 32; o > 0; o >>= 1) val += __shfl_xor(val, o);
    __shared__ float sred[4];
    if ((threadIdx.x & 63) == 0) sred[threadIdx.x >> 6] = val;
    __syncthreads();
    if (threadIdx.x == 0)
        atomicAdd(out, (sred[0] + sred[1] + sred[2] + sred[3]) * (0.5f / 131072.0f));
}

extern "C" void kernel_launch(void* const* d_in, const int* in_sizes, int n_in,
                              void* d_out, int out_size, void* d_ws, size_t ws_size,
                              hipStream_t stream) {
    const float* Bmat  = (const float*)d_in[1];
    const float* W0    = (const float*)d_in[2];
    const float* b0    = (const float*)d_in[3];
    const float* W1    = (const float*)d_in[4];
    const float* b1    = (const float*)d_in[5];
    const float* W2    = (const float*)d_in[6];
    const float* b2    = (const float*)d_in[7];
    const float* W3    = (const float*)d_in[8];
    const float* b3    = (const float*)d_in[9];
    const float* W4    = (const float*)d_in[10];
    const float* b4    = (const float*)d_in[11];
    const float* image = (const float*)d_in[12];
    const float* ktraj = (const float*)d_in[13];

    char* ws = (char*)d_ws;
    short* wbf    = (short*)(ws);                  // 135 KB
    float* brev   = (float*)(ws + (256u << 10));   // 2 KB
    float* ptx    = (float*)(ws + (320u << 10));   // 32 KB
    float* pty    = (float*)(ws + (352u << 10));   // 32 KB
    float* ptz    = (float*)(ws + (384u << 10));   // 16 KB
    float* tab    = (float*)(ws + (1u << 20));     // 4 MB
    float* d_nat  = (float*)(ws + (5u << 20));     // 4 MB
    short* d_proj = (short*)(ws + (9u << 20));     // 2 MB
    float* part   = (float*)(ws + (11u << 20));    // 8 MB
    float* outf   = (float*)d_out;

    hipLaunchKernelGGL(k_prep,      dim3(2394), dim3(256), 0, stream,
                       ktraj, W0, W1, W2, W3, W4, b0, b1, b2, b3, Bmat,
                       tab, wbf, brev, ptx, pty, ptz);
    hipLaunchKernelGGL(k_siren,     dim3(8192), dim3(256), 0, stream,
                       ptx, pty, ptz, brev, b4, wbf, image, d_nat);
    hipLaunchKernelGGL(k_transpose, dim3(128),  dim3(256), 0, stream, d_nat, d_proj);
    hipLaunchKernelGGL(k_project,   dim3(512),  dim3(256), 0, stream, d_proj, tab, part);
    hipMemsetAsync(d_out, 0, sizeof(float), stream);
    hipLaunchKernelGGL(k_loss,      dim3(512),  dim3(256), 0, stream, part, outf);
}

// Round 6
// 248.375 us; speedup vs baseline: 2.3920x; 2.3920x over previous
//
#include <hip/hip_runtime.h>
#include <hip/hip_bf16.h>

#define K30REV 4.77464829275686f   /* 30/(2*pi) */
#define ASTRIDE 272                /* A-tile row stride in bytes: 256 + 16 pad */

typedef __attribute__((ext_vector_type(4))) float f32x4;
typedef __attribute__((ext_vector_type(8))) short s16x8;

__device__ __forceinline__ short f2bf(float f) {
    union { float f; unsigned u; } a; a.f = f;
    unsigned r = a.u + 0x7fffu + ((a.u >> 16) & 1u);
    return (short)(r >> 16);
}

__device__ __forceinline__ unsigned pk2(float a, float b) {
    union { __hip_bfloat162 h; unsigned u; } cv;
    cv.h = __float22bfloat162_rn(make_float2(a, b));
    return cv.u;
}

// ---------- merged prep ----------
// [0,524288): radial tables tab[n][{cosA,sinA,cosB,sinB}][128]
// [+65536): Wswz — hidden weights in MFMA-fragment-contiguous order:
//           wswz[layer*16384 + ntg*2048 + ks*512 + lane*8 + j]
//             = W_layer[(ntg*16 + (lane&15))*128 + ks*32 + (lane>>4)*8 + j]
// [+2048): W4 zero-padded [16][128] ; [+512): brev = bias*K30REV ; [+20480): pt tables
__global__ void k_prep(const float* __restrict__ ktraj,
                       const float* __restrict__ W0, const float* __restrict__ W1,
                       const float* __restrict__ W2, const float* __restrict__ W3,
                       const float* __restrict__ W4,
                       const float* __restrict__ b0, const float* __restrict__ b1,
                       const float* __restrict__ b2, const float* __restrict__ b3,
                       const float* __restrict__ Bmat,
                       float* __restrict__ tab, short* __restrict__ wswz,
                       short* __restrict__ w4pad, float* __restrict__ brev,
                       float* __restrict__ ptx, float* __restrict__ pty,
                       float* __restrict__ ptz) {
    int i = blockIdx.x * 256 + threadIdx.x;
    if (i < 524288) {
        int n = i >> 8, s = i & 255;
        if (s < 128) {
            float a = ktraj[n] * (float)s;
            tab[n * 512 + s]       = __cosf(a);
            tab[n * 512 + 128 + s] = __sinf(a);
        } else {
            int y = s - 128;
            float a = ktraj[2048 + n] * (float)y;
            tab[n * 512 + 256 + y] = __cosf(a);
            tab[n * 512 + 384 + y] = __sinf(a);
        }
        return;
    }
    i -= 524288;
    if (i < 65536) {
        int layer = i >> 14, q = i & 16383;
        int ntg = q >> 11, ks = (q >> 9) & 3, rem = q & 511;
        int ln = rem >> 3, j = rem & 7;
        int row = ntg * 16 + (ln & 15);
        int col = ks * 32 + (ln >> 4) * 8 + j;
        const float* src = (layer == 0) ? W0 : (layer == 1) ? W1 : (layer == 2) ? W2 : W3;
        wswz[i] = f2bf(src[row * 128 + col]);
        return;
    }
    i -= 65536;
    if (i < 2048) {
        int row = i >> 7, col = i & 127;
        w4pad[i] = f2bf(row == 0 ? W4[col] : 0.0f);
        return;
    }
    i -= 2048;
    if (i < 512) {
        int l = i >> 7, col = i & 127;
        const float* src = (l == 0) ? b0 : (l == 1) ? b1 : (l == 2) ? b2 : b3;
        brev[i] = src[col] * K30REV;
        return;
    }
    i -= 512;
    if (i < 8192) {             // ptx
        int x = i >> 6, e = i & 63;
        ptx[i] = ((x + 0.5f) * (1.0f / 128.0f)) * Bmat[e * 3 + 0];
        return;
    }
    i -= 8192;
    if (i < 8192) {             // pty
        int y = i >> 6, e = i & 63;
        pty[i] = ((y + 0.5f) * (1.0f / 128.0f)) * Bmat[e * 3 + 1];
        return;
    }
    i -= 8192;
    if (i < 4096) {             // ptz
        int z = i >> 6, e = i & 63;
        ptz[i] = ((z + 0.5f) * (1.0f / 64.0f)) * Bmat[e * 3 + 2];
    }
}

// ---------- kernel 1: fused encode + SIREN + (vol - image) ----------
// 256 thr = 4 waves as 2(row: 64 rows)x2(col: 64 neurons) over a 128-row tile.
// 34.8 KB LDS -> 4 INDEPENDENT blocks/CU (16 waves, 4 barrier domains: one
// block's barrier drain overlaps the other 3 blocks' compute).
// af = weights in fragment-contiguous Wswz: each load = base + lane*16B,
// 1 KB fully coalesced (no 16-scattered-line L1 pattern, no per-lane addr math).
// Swapped MFMA: mfma(af=W, bf=A rows) -> lane: A-row=l15, neuron=l4*4+jj
// -> activation writeback = one ds_write_b64 (4 consecutive bf16 cols).
__launch_bounds__(256, 4)
__global__ void k_siren(const float* __restrict__ ptx, const float* __restrict__ pty,
                        const float* __restrict__ ptz,
                        const float* __restrict__ brev,
                        const float* __restrict__ b4,
                        const short* __restrict__ wswz,
                        const short* __restrict__ w4pad,
                        const float* __restrict__ image,
                        float* __restrict__ d_nat) {
    __shared__ alignas(16) char Abuf[128 * ASTRIDE];   // 34816 B
    const int tid  = threadIdx.x;
    const int lane = tid & 63;
    const int w    = tid >> 6;
    const int wr   = w >> 1;        // 0..1: rows wr*64 .. +63
    const int wc   = w & 1;         // 0..1: neurons wc*64 .. +63
    const int l15  = lane & 15;
    const int l4   = lane >> 4;
    const int nbase = blockIdx.x * 128;

    // ---- encode: 2 threads per row, 32 freqs each; p = ptx[x]+pty[y]+ptz[z] ----
    {
        int row = tid >> 1, h = tid & 1;
        int n = nbase + row;
        int x = n >> 13, y = (n >> 6) & 127, z = n & 63;
        const float* pxr = ptx + x * 64 + h * 32;
        const float* pyr = pty + y * 64 + h * 32;
        const float* pzr = ptz + z * 64 + h * 32;
        char* rowp = Abuf + row * ASTRIDE + h * 64;
        #pragma unroll
        for (int eb = 0; eb < 32; eb += 8) {
            f32x4 xa = *(const f32x4*)(pxr + eb),     xb = *(const f32x4*)(pxr + eb + 4);
            f32x4 ya = *(const f32x4*)(pyr + eb),     yb = *(const f32x4*)(pyr + eb + 4);
            f32x4 za = *(const f32x4*)(pzr + eb),     zb = *(const f32x4*)(pzr + eb + 4);
            float p[8];
            #pragma unroll
            for (int j = 0; j < 4; j++) {
                p[j]     = xa[j] + ya[j] + za[j];
                p[4 + j] = xb[j] + yb[j] + zb[j];
            }
            unsigned vs[4], vc[4];
            #pragma unroll
            for (int j = 0; j < 4; j++) {
                vs[j] = pk2(__builtin_amdgcn_sinf(p[2 * j]), __builtin_amdgcn_sinf(p[2 * j + 1]));
                vc[j] = pk2(__builtin_amdgcn_cosf(p[2 * j]), __builtin_amdgcn_cosf(p[2 * j + 1]));
            }
            *(uint4*)(rowp + 2 * eb)       = *(uint4*)vs;   // sin block: bytes 0..127
            *(uint4*)(rowp + 128 + 2 * eb) = *(uint4*)vc;   // cos block: bytes 128..255
        }
    }

    // ---- layer-invariant LDS addresses ----
    int rbase[4], wbase2[4];
    #pragma unroll
    for (int rt = 0; rt < 4; rt++) {
        int rowoff = (wr * 64 + rt * 16 + l15) * ASTRIDE;
        rbase[rt]  = rowoff + l4 * 16;              // + ks*64 on read
        wbase2[rt] = rowoff + wc * 128 + l4 * 8;    // + nt*32 on write
    }
    const short* Wlane = wswz + wc * 8192 + lane * 8;   // + layer*16384 + nt*2048 + ks*512

    __syncthreads();

    // ---- 4 hidden layers ----
    #pragma unroll 1
    for (int layer = 0; layer < 4; layer++) {
        const short* W = Wlane + layer * 16384;
        f32x4 acc[4][4];
        #pragma unroll
        for (int rt = 0; rt < 4; rt++)
            #pragma unroll
            for (int nt = 0; nt < 4; nt++)
                acc[rt][nt] = (f32x4){0.f, 0.f, 0.f, 0.f};

        #pragma unroll
        for (int ks = 0; ks < 4; ks++) {
            s16x8 bfr[4];
            #pragma unroll
            for (int rt = 0; rt < 4; rt++)
                bfr[rt] = *(const s16x8*)(Abuf + rbase[rt] + ks * 64);
            #pragma unroll
            for (int nt = 0; nt < 4; nt++) {
                s16x8 af = *(const s16x8*)(W + nt * 2048 + ks * 512);
                #pragma unroll
                for (int rt = 0; rt < 4; rt++)
                    acc[rt][nt] = __builtin_amdgcn_mfma_f32_16x16x32_bf16(af, bfr[rt], acc[rt][nt], 0, 0, 0);
            }
        }
        __syncthreads();   // all reads done before overwrite
        #pragma unroll
        for (int nt = 0; nt < 4; nt++) {
            f32x4 bb = *(const f32x4*)(brev + layer * 128 + wc * 64 + nt * 16 + l4 * 4);
            #pragma unroll
            for (int rt = 0; rt < 4; rt++) {
                float s0 = __builtin_amdgcn_sinf(fmaf(acc[rt][nt][0], K30REV, bb[0]));
                float s1 = __builtin_amdgcn_sinf(fmaf(acc[rt][nt][1], K30REV, bb[1]));
                float s2 = __builtin_amdgcn_sinf(fmaf(acc[rt][nt][2], K30REV, bb[2]));
                float s3 = __builtin_amdgcn_sinf(fmaf(acc[rt][nt][3], K30REV, bb[3]));
                uint2 pk; pk.x = pk2(s0, s1); pk.y = pk2(s2, s3);
                *(uint2*)(Abuf + wbase2[rt] + nt * 32) = pk;
            }
        }
        __syncthreads();   // writes visible before next layer reads
    }

    // ---- final layer (unswapped): af=A rows, bf=W4 padded; 32 rows per wave ----
    {
        const short* W4p = w4pad + l15 * 128 + l4 * 8;
        f32x4 a4[2];
        a4[0] = (f32x4){0.f, 0.f, 0.f, 0.f};
        a4[1] = (f32x4){0.f, 0.f, 0.f, 0.f};
        #pragma unroll
        for (int ks = 0; ks < 4; ks++) {
            s16x8 bw = *(const s16x8*)(W4p + ks * 32);
            #pragma unroll
            for (int q = 0; q < 2; q++) {
                int row = w * 32 + q * 16 + l15;
                s16x8 af = *(const s16x8*)(Abuf + row * ASTRIDE + ks * 64 + l4 * 16);
                a4[q] = __builtin_amdgcn_mfma_f32_16x16x32_bf16(af, bw, a4[q], 0, 0, 0);
            }
        }
        if (l15 == 0) {
            float b4v = b4[0];
            #pragma unroll
            for (int q = 0; q < 2; q++) {
                int n = nbase + w * 32 + q * 16 + l4 * 4;
                const f32x4 img = *(const f32x4*)(image + n);
                f32x4 dv;
                #pragma unroll
                for (int jj = 0; jj < 4; jj++) dv[jj] = a4[q][jj] + b4v - img[jj];
                *(f32x4*)(d_nat + n) = dv;
            }
        }
    }
}

// ---------- kernel 1.5: d_nat [x][y][z] fp32 -> d_proj [z][x*128+y] bf16 ----------
__global__ void k_transpose(const float* __restrict__ d_nat, short* __restrict__ d_proj) {
    __shared__ float t[128][65];
    int x = blockIdx.x;
    for (int i = threadIdx.x; i < 8192; i += 256)
        t[i >> 6][i & 63] = d_nat[x * 8192 + i];
    __syncthreads();
    for (int i = threadIdx.x; i < 8192; i += 256) {
        int z = i >> 7, y = i & 127;
        d_proj[z * 16384 + x * 128 + y] = f2bf(t[y][z]);
    }
}

// ---------- kernel 2: NUDFT GEMM (M=64 z, N=2048 k-samples, K=16384 pixels) ----------
__launch_bounds__(256, 2)
__global__ void k_project(const short* __restrict__ d_proj, const float* __restrict__ tab,
                          float* __restrict__ part) {
    __shared__ alignas(16) float lt[4 * 32 * 132];   // 67584 B; reused as reduce buffer
    const int tid  = threadIdx.x;
    const int lane = tid & 63;
    const int w    = tid >> 6;
    const int l15  = lane & 15;
    const int l4   = lane >> 4;
    const int nblk = blockIdx.x & 63;
    const int ksp  = blockIdx.x >> 6;
    const int nbase = nblk * 32;

    for (int i = tid; i < 16384; i += 256) {
        int nl = i >> 9, r = i & 511;
        int t = r >> 7, e = r & 127;
        lt[(t * 32 + nl) * 132 + e] = tab[(nbase + nl) * 512 + r];
    }
    __syncthreads();

    f32x4 ar[4][2], ai[4][2];
    #pragma unroll
    for (int rt = 0; rt < 4; rt++)
        #pragma unroll
        for (int nt = 0; nt < 2; nt++) {
            ar[rt][nt] = (f32x4){0.f, 0.f, 0.f, 0.f};
            ai[rt][nt] = (f32x4){0.f, 0.f, 0.f, 0.f};
        }

    const int p2base = ksp * 2048 + w * 512;
    #pragma unroll 1
    for (int ks = 0; ks < 16; ks++) {
        int p2c = p2base + ks * 32;
        s16x8 afr[4];
        #pragma unroll
        for (int rt = 0; rt < 4; rt++)
            afr[rt] = *(const s16x8*)(d_proj + (rt * 16 + l15) * 16384 + p2c + l4 * 8);
        int p2 = p2c + l4 * 8;
        int x = p2 >> 7, y0 = p2 & 127;
        #pragma unroll
        for (int nt = 0; nt < 2; nt++) {
            int nl = nt * 16 + l15;
            float cA = lt[nl * 132 + x];
            float sA = lt[(32 + nl) * 132 + x];
            const float* cB = &lt[(64 + nl) * 132 + y0];
            const float* sB = &lt[(96 + nl) * 132 + y0];
            s16x8 bc, bs;
            #pragma unroll
            for (int j = 0; j < 8; j++) {
                float cb = cB[j], sb = sB[j];
                bc[j] = f2bf(cA * cb - sA * sb);
                bs[j] = f2bf(sA * cb + cA * sb);
            }
            #pragma unroll
            for (int rt = 0; rt < 4; rt++) {
                ar[rt][nt] = __builtin_amdgcn_mfma_f32_16x16x32_bf16(afr[rt], bc, ar[rt][nt], 0, 0, 0);
                ai[rt][nt] = __builtin_amdgcn_mfma_f32_16x16x32_bf16(afr[rt], bs, ai[rt][nt], 0, 0, 0);
            }
        }
    }
    __syncthreads();   // tables dead; reuse lt as reduce buffer
    float* red = lt;
    #pragma unroll
    for (int rt = 0; rt < 4; rt++)
        #pragma unroll
        for (int nt = 0; nt < 2; nt++)
            #pragma unroll
            for (int jj = 0; jj < 4; jj++) {
                int z = rt * 16 + l4 * 4 + jj;
                int q = nt * 16 + l15;
                red[(w * 64 + z) * 64 + q * 2 + 0] = ar[rt][nt][jj];
                red[(w * 64 + z) * 64 + q * 2 + 1] = ai[rt][nt][jj];
            }
    __syncthreads();
    for (int i = tid; i < 4096; i += 256) {
        int z = i >> 6, q = i & 63;
        float s = red[z * 64 + q] + red[4096 + z * 64 + q] + red[8192 + z * 64 + q] + red[12288 + z * 64 + q];
        part[((ksp * 64 + z) * 2048 + nbase + (q >> 1)) * 2 + (q & 1)] = s;
    }
}

// ---------- kernel 3: sum K-split partials, square, reduce to loss ----------
__global__ void k_loss(const float* __restrict__ part, float* __restrict__ out) {
    int g = blockIdx.x * 256 + threadIdx.x;   // 131072 (z,n) pairs
    int z = g >> 11, n = g & 2047;
    float r = 0.f, im = 0.f;
    #pragma unroll
    for (int ksp = 0; ksp < 8; ksp++) {
        const float2 v = *(const float2*)(part + ((ksp * 64 + z) * 2048 + n) * 2);
        r += v.x; im += v.y;
    }
    float val = r * r + im * im;
    #pragma unroll
    for (int o = 32; o > 0; o >>= 1) val += __shfl_xor(val, o);
    __shared__ float sred[4];
    if ((threadIdx.x & 63) == 0) sred[threadIdx.x >> 6] = val;
    __syncthreads();
    if (threadIdx.x == 0)
        atomicAdd(out, (sred[0] + sred[1] + sred[2] + sred[3]) * (0.5f / 131072.0f));
}

extern "C" void kernel_launch(void* const* d_in, const int* in_sizes, int n_in,
                              void* d_out, int out_size, void* d_ws, size_t ws_size,
                              hipStream_t stream) {
    const float* Bmat  = (const float*)d_in[1];
    const float* W0    = (const float*)d_in[2];
    const float* b0    = (const float*)d_in[3];
    const float* W1    = (const float*)d_in[4];
    const float* b1    = (const float*)d_in[5];
    const float* W2    = (const float*)d_in[6];
    const float* b2    = (const float*)d_in[7];
    const float* W3    = (const float*)d_in[8];
    const float* b3    = (const float*)d_in[9];
    const float* W4    = (const float*)d_in[10];
    const float* b4    = (const float*)d_in[11];
    const float* image = (const float*)d_in[12];
    const float* ktraj = (const float*)d_in[13];

    char* ws = (char*)d_ws;
    short* w4pad  = (short*)(ws);                  // 4 KB
    float* brev   = (float*)(ws + (8u << 10));     // 2 KB
    float* ptx    = (float*)(ws + (64u << 10));    // 32 KB
    float* pty    = (float*)(ws + (96u << 10));    // 32 KB
    float* ptz    = (float*)(ws + (128u << 10));   // 16 KB
    short* wswz   = (short*)(ws + (160u << 10));   // 128 KB (fragment-contiguous W0..W3)
    float* tab    = (float*)(ws + (1u << 20));     // 4 MB
    float* d_nat  = (float*)(ws + (5u << 20));     // 4 MB
    short* d_proj = (short*)(ws + (9u << 20));     // 2 MB
    float* part   = (float*)(ws + (11u << 20));    // 8 MB
    float* outf   = (float*)d_out;

    hipLaunchKernelGGL(k_prep,      dim3(2394), dim3(256), 0, stream,
                       ktraj, W0, W1, W2, W3, W4, b0, b1, b2, b3, Bmat,
                       tab, wswz, w4pad, brev, ptx, pty, ptz);
    hipLaunchKernelGGL(k_siren,     dim3(8192), dim3(256), 0, stream,
                       ptx, pty, ptz, brev, b4, wswz, w4pad, image, d_nat);
    hipLaunchKernelGGL(k_transpose, dim3(128),  dim3(256), 0, stream, d_nat, d_proj);
    hipLaunchKernelGGL(k_project,   dim3(512),  dim3(256), 0, stream, d_proj, tab, part);
    hipMemsetAsync(d_out, 0, sizeof(float), stream);
    hipLaunchKernelGGL(k_loss,      dim3(512),  dim3(256), 0, stream, part, outf);
}